// Round 5
// baseline (466.007 us; speedup 1.0000x reference)
//
#include <hip/hip_runtime.h>
#include <math.h>

// NoisyTopkRouter: B=8,T=4096,NE=1024,E=16,TOPK=2,LIN=1824
// tokens = 32768; streamed features = 1792 (city-32 folded into a constant)
// out = [router 32768*16][indices 32768*2][gate1 32768*16] all f32
//
// R5: two-kernel split-K. Kernel1: block = 512 thr / 128 tokens / HALF of K
// (14 of 28 chunks); grid 512 = 2 blocks/CU so one block's barriers overlap
// the other's compute. Lane tile 8 tok x 8 e (16 FMA per ds_read_b128).
// 8 waves = 8 k-slabs per chunk; in-block LDS reduce; [128][32] fp32 partial
// -> d_ws. Kernel2: sum both halves + city/bias const, epilogue, store.

#define NCHUNK_HALF 14
#define I_OFF 524288        // 32768*16
#define G_OFF 589824        // 524288 + 32768*2
#define SA 68               // pad 64->68: 2-way banks (free, m136)
#define SW 36
#define SS 36

__device__ __forceinline__ float softplus_f(float x) {
  // jax.nn.softplus = max(x,0) + log1p(exp(-|x|))
  return fmaxf(x, 0.0f) + log1pf(expf(-fabsf(x)));
}

__device__ __forceinline__ float get_comp(const float4& v, int kk) {
  return kk == 0 ? v.x : kk == 1 ? v.y : kk == 2 ? v.z : v.w;
}

__global__ __launch_bounds__(512, 4) void gemm_half_kernel(
    const float* __restrict__ mh, const float* __restrict__ dt,
    const float* __restrict__ dd, const float* __restrict__ rg,
    const float* __restrict__ de,
    const float* __restrict__ w_route, const float* __restrict__ w_noise,
    float* __restrict__ ws) {
  // A [128][68] = 8704 f | W [64][36] = 2304 f ; scores [128][36] overlay A
  __shared__ float smem[11008];
  float* sA = smem;
  float* sW = smem + 8704;
  float* sS = smem;  // 4608 floats, fits inside A region

  const int tid = threadIdx.x;
  const int w   = tid >> 6;        // wave 0..7: k-slab [w*8, w*8+8) per chunk
  const int ln  = tid & 63;
  const int tg  = ln & 15;         // tokens {tg + 16j}, j=0..7
  const int eg  = ln >> 4;         // e-cols eg*8..eg*8+7 (of 32 = route|noise)
  const int tb  = blockIdx.x >> 1;
  const int h   = blockIdx.x & 1;  // K half
  const int blockTok = tb * 128;
  const int g0 = h * NCHUNK_HALF;

  float4 accL[8], accH[8];
#pragma unroll
  for (int j = 0; j < 8; ++j) {
    accL[j] = make_float4(0.f, 0.f, 0.f, 0.f);
    accH[j] = make_float4(0.f, 0.f, 0.f, 0.f);
  }

  // staging coords (coalesced): A 128x16 f4 -> 4 f4/thread; W 64x8 f4 -> 1
  const int arow = tid >> 4, acol = (tid & 15) * 4;
  const int wrow = tid >> 3, wcol = tid & 7;

  float4 AR0, AR1, AR2, AR3, WR;  // named regs: no scratch spill

  auto a_src = [&](int g, int row) -> const float* {
    const float* base; int stride;
    if (g < 16)      { base = mh + g * 64;        stride = 1024; }
    else if (g < 20) { base = dt + (g - 16) * 64; stride = 256; }
    else if (g < 24) { base = dd + (g - 20) * 64; stride = 256; }
    else if (g < 26) { base = rg + (g - 24) * 64; stride = 128; }
    else             { base = de + (g - 26) * 64; stride = 128; }
    return base + (size_t)(blockTok + row) * stride;
  };

  auto prefetch = [&](int g) {
    AR0 = *(const float4*)(a_src(g, arow +  0) + acol);
    AR1 = *(const float4*)(a_src(g, arow + 32) + acol);
    AR2 = *(const float4*)(a_src(g, arow + 64) + acol);
    AR3 = *(const float4*)(a_src(g, arow + 96) + acol);
    const int kb = g * 64 + ((g >= 16) ? 32 : 0);  // skip city rows 1024..1055
    const float* wsrc = (wcol < 4)
        ? (w_route + (kb + wrow) * 16 + wcol * 4)
        : (w_noise + (kb + wrow) * 16 + (wcol - 4) * 4);
    WR = *(const float4*)wsrc;
  };

  prefetch(g0);

  for (int c = 0; c < NCHUNK_HALF; ++c) {
    __syncthreads();  // previous chunk's reads done -> buffers free
    *(float4*)&sA[(arow +  0) * SA + acol] = AR0;
    *(float4*)&sA[(arow + 32) * SA + acol] = AR1;
    *(float4*)&sA[(arow + 64) * SA + acol] = AR2;
    *(float4*)&sA[(arow + 96) * SA + acol] = AR3;
    *(float4*)&sW[wrow * SW + wcol * 4] = WR;
    __syncthreads();  // tile visible

    if (c + 1 < NCHUNK_HALF) prefetch(g0 + c + 1);  // flies over compute

    const int k0 = w * 8;
#pragma unroll
    for (int q = 0; q < 2; ++q) {
      const int koff = k0 + q * 4;
      float4 a[8];
#pragma unroll
      for (int j = 0; j < 8; ++j)
        a[j] = *(const float4*)&sA[(tg + 16 * j) * SA + koff];
#pragma unroll
      for (int kk = 0; kk < 4; ++kk) {
        float4 wv0 = *(const float4*)&sW[(koff + kk) * SW + eg * 8];      // bcast
        float4 wv1 = *(const float4*)&sW[(koff + kk) * SW + eg * 8 + 4];  // bcast
#pragma unroll
        for (int j = 0; j < 8; ++j) {
          const float s = get_comp(a[j], kk);
          accL[j].x = fmaf(s, wv0.x, accL[j].x);
          accL[j].y = fmaf(s, wv0.y, accL[j].y);
          accL[j].z = fmaf(s, wv0.z, accL[j].z);
          accL[j].w = fmaf(s, wv0.w, accL[j].w);
          accH[j].x = fmaf(s, wv1.x, accH[j].x);
          accH[j].y = fmaf(s, wv1.y, accH[j].y);
          accH[j].z = fmaf(s, wv1.z, accH[j].z);
          accH[j].w = fmaf(s, wv1.w, accH[j].w);
        }
      }
    }
  }

  // ---- 8-slab reduction: serial RMW rounds into sS[128][36] ----
  __syncthreads();  // all reads of sA done before overlaying
  for (int r = 0; r < 8; ++r) {
    if (w == r) {
#pragma unroll
      for (int j = 0; j < 8; ++j) {
        float* p = &sS[(tg + 16 * j) * SS + eg * 8];
        if (r == 0) {
          *(float4*)(p)     = accL[j];
          *(float4*)(p + 4) = accH[j];
        } else {
          float4 x0 = *(float4*)(p), x1 = *(float4*)(p + 4);
          x0.x += accL[j].x; x0.y += accL[j].y; x0.z += accL[j].z; x0.w += accL[j].w;
          x1.x += accH[j].x; x1.y += accH[j].y; x1.z += accH[j].z; x1.w += accH[j].w;
          *(float4*)(p)     = x0;
          *(float4*)(p + 4) = x1;
        }
      }
    }
    __syncthreads();
  }

  // ---- write [128][32] partial to ws (coalesced, 8 floats/thread) ----
  float* dst = ws + (size_t)(tb * 2 + h) * 4096;
  const int f = tid * 8;
  const int row = f >> 5, col = f & 31;
  *(float4*)&dst[f]     = *(float4*)&sS[row * SS + col];
  *(float4*)&dst[f + 4] = *(float4*)&sS[row * SS + col + 4];
}

__global__ __launch_bounds__(256, 4) void epilogue_kernel(
    const float* __restrict__ ws, const float* __restrict__ cemb_all,
    const int* __restrict__ city_index,
    const float* __restrict__ w_route, const float* __restrict__ b_route,
    const float* __restrict__ w_noise, const float* __restrict__ b_noise,
    const float* __restrict__ eps, float* __restrict__ out) {
  __shared__ float city_l[32];
  const int tid = threadIdx.x;

  if (tid < 32) {
    const int e = tid & 15;
    const float* wsrc = (tid < 16) ? w_route : w_noise;
    const float* bsrc = (tid < 16) ? b_route : b_noise;
    const float* ce = cemb_all + city_index[0] * 32;
    float s = bsrc[e];
#pragma unroll
    for (int j = 0; j < 32; ++j) s = fmaf(ce[j], wsrc[(1024 + j) * 16 + e], s);
    city_l[tid] = s;
  }
  __syncthreads();

  const int t  = blockIdx.x * 256 + tid;   // token
  const int tb = t >> 7, r = t & 127;
  const float* p0 = ws + (size_t)(tb * 2 + 0) * 4096 + r * 32;
  const float* p1 = ws + (size_t)(tb * 2 + 1) * 4096 + r * 32;

  float l[32];
#pragma unroll
  for (int e4 = 0; e4 < 8; ++e4) {
    float4 a = *(const float4*)(p0 + e4 * 4);
    float4 b = *(const float4*)(p1 + e4 * 4);
    l[e4 * 4 + 0] = a.x + b.x + city_l[e4 * 4 + 0];
    l[e4 * 4 + 1] = a.y + b.y + city_l[e4 * 4 + 1];
    l[e4 * 4 + 2] = a.z + b.z + city_l[e4 * 4 + 2];
    l[e4 * 4 + 3] = a.w + b.w + city_l[e4 * 4 + 3];
  }

  const float* ep = eps + (size_t)t * 16;
  float n[16];
#pragma unroll
  for (int e = 0; e < 16; ++e)
    n[e] = fmaf(ep[e], softplus_f(l[16 + e]), l[e]);

  // top-2, lowest-index tie-break (matches lax.top_k)
  float m1 = -INFINITY; int i1 = 0;
#pragma unroll
  for (int e = 0; e < 16; ++e)
    if (n[e] > m1) { m1 = n[e]; i1 = e; }
  float m2 = -INFINITY; int i2 = 0;
#pragma unroll
  for (int e = 0; e < 16; ++e)
    if (e != i1 && n[e] > m2) { m2 = n[e]; i2 = e; }

  float ex[16], Z = 0.f;
#pragma unroll
  for (int e = 0; e < 16; ++e) { ex[e] = expf(n[e] - m1); Z += ex[e]; }
  const float invZ  = 1.0f / Z;
  const float invZ2 = 1.0f / (1.0f + expf(m2 - m1));  // ex[i1]=1

  float rr[16], g1[16];
#pragma unroll
  for (int e = 0; e < 16; ++e) {
    rr[e] = (e == i1 || e == i2) ? ex[e] * invZ2 : 0.0f;
    g1[e] = ex[e] * invZ;
  }

  float* ro = out + (size_t)t * 16;
#pragma unroll
  for (int e4 = 0; e4 < 4; ++e4)
    *(float4*)(ro + e4 * 4) = make_float4(rr[e4*4], rr[e4*4+1], rr[e4*4+2], rr[e4*4+3]);

  out[I_OFF + (size_t)t * 2 + 0] = (float)i1;
  out[I_OFF + (size_t)t * 2 + 1] = (float)i2;

  float* go = out + G_OFF + (size_t)t * 16;
#pragma unroll
  for (int e4 = 0; e4 < 4; ++e4)
    *(float4*)(go + e4 * 4) = make_float4(g1[e4*4], g1[e4*4+1], g1[e4*4+2], g1[e4*4+3]);
}

extern "C" void kernel_launch(void* const* d_in, const int* in_sizes, int n_in,
                              void* d_out, int out_size, void* d_ws, size_t ws_size,
                              hipStream_t stream) {
  const float* mh = (const float*)d_in[0];   // [8,4096,1024]
  const float* dt = (const float*)d_in[1];   // [8,4096,256]
  const float* dd = (const float*)d_in[2];   // [8,4096,256]
  const float* rg = (const float*)d_in[3];   // [8,4096,128]
  const float* de = (const float*)d_in[4];   // [8,4096,128]
  const float* ce = (const float*)d_in[5];   // [4,32]
  const float* wr = (const float*)d_in[6];   // [1824,16]
  const float* br = (const float*)d_in[7];   // [16]
  const float* wn = (const float*)d_in[8];   // [1824,16]
  const float* bn = (const float*)d_in[9];   // [16]
  const float* ep = (const float*)d_in[10];  // [8,4096,16]
  const int*   ci = (const int*)d_in[11];    // scalar
  float* out = (float*)d_out;
  float* ws  = (float*)d_ws;   // needs 256*2*4096*4 = 8.39 MB

  gemm_half_kernel<<<512, 512, 0, stream>>>(mh, dt, dd, rg, de, wr, wn, ws);
  epilogue_kernel<<<128, 256, 0, stream>>>(ws, ce, ci, wr, br, wn, bn, ep, out);
}